// Round 4
// baseline (422.636 us; speedup 1.0000x reference)
//
#include <hip/hip_runtime.h>

#define HDIM 2048
#define HH (HDIM * HDIM)          // 4,194,304
#define NIDX 2000000
#define BINS 256
#define NCOPY 16                  // spread copies of the global histogram
#define LOSS_BLOCKS 1024

// workspace layout (bytes)  (total ~32.1 MB, within known-good ws footprint)
#define PART_OFF     0                      // double partials[LOSS_BLOCKS] = 8 KB
#define HIST_OFF     8192                   // uint hist[NCOPY][6][256] = 96 KB
#define TAB_OFF      106496                 // float tables[3][256] = 3 KB
#define PACKED_D_OFF 1048576                // uint packed_d[HH] = 16 MB (bins 0..23, count 24..31)
#define PACKED_R_OFF 17825792               // uint packed_r[HH] = 16 MB
#define WS_ZERO_BYTES (TAB_OFF + 3072)      // zero partials+hist+tab in one tiny memset

// Pack 3 channel bins (mask folded in: v*0 -> bin 0) into bits 0..23 of one uint
// per pixel; high byte left 0 (scatter_kernel accumulates sample counts there).
__global__ __launch_bounds__(256) void pack_kernel(
    const float* __restrict__ ref, const float* __restrict__ tgt,
    const float* __restrict__ msrc, const float* __restrict__ mtar,
    unsigned* __restrict__ packed_d, unsigned* __restrict__ packed_r)
{
    const int stride = gridDim.x * 256;
    for (int g = blockIdx.x * 256 + threadIdx.x; g < HH / 4; g += stride) {
        const int p = g * 4;
        const float4 ms4 = *(const float4*)(msrc + p);
        const float4 mt4 = *(const float4*)(mtar + p);
        const float ms[4] = {ms4.x, ms4.y, ms4.z, ms4.w};
        const float mt[4] = {mt4.x, mt4.y, mt4.z, mt4.w};
        unsigned od[4] = {0, 0, 0, 0}, orr[4] = {0, 0, 0, 0};
#pragma unroll
        for (int c = 0; c < 3; c++) {
            const float4 rv = *(const float4*)(ref + c * HH + p);
            const float4 tv = *(const float4*)(tgt + c * HH + p);
            const float r[4] = {rv.x, rv.y, rv.z, rv.w};
            const float t[4] = {tv.x, tv.y, tv.z, tv.w};
#pragma unroll
            for (int k = 0; k < 4; k++) {
                // match reference op order: ((x+1)*0.5)*255, then * mask
                const float vd = ((r[k] + 1.0f) * 0.5f) * 255.0f * ms[k];
                const float vr = ((t[k] + 1.0f) * 0.5f) * 255.0f * mt[k];
                const unsigned bd = (unsigned)(int)fminf(fmaxf(floorf(vd), 0.0f), 255.0f);
                const unsigned br = (unsigned)(int)fminf(fmaxf(floorf(vr), 0.0f), 255.0f);
                od[k]  |= bd << (8 * c);
                orr[k] |= br << (8 * c);
            }
        }
        *(uint4*)(packed_d + p) = make_uint4(od[0], od[1], od[2], od[3]);
        *(uint4*)(packed_r + p) = make_uint4(orr[0], orr[1], orr[2], orr[3]);
    }
}

// Scatter sample counts into the high byte of packed_d / packed_r.
// Fire-and-forget u32 atomics: no gather latency chains.
// Max multiplicity over 4M cells with 2M uniform draws is ~10 (Poisson tail);
// a byte cannot overflow in practice, so no carry into bit 32 / the bins.
__global__ __launch_bounds__(256) void scatter_kernel(
    const int* __restrict__ i0, const int* __restrict__ i1,
    const int* __restrict__ i2, const int* __restrict__ i3,
    unsigned* __restrict__ packed_d, unsigned* __restrict__ packed_r)
{
    const int stride = gridDim.x * 256;
    for (int q = blockIdx.x * 256 + threadIdx.x; q < NIDX / 4; q += stride) {
        const int4 a = ((const int4*)i0)[q];
        const int4 b = ((const int4*)i1)[q];
        const int4 c = ((const int4*)i2)[q];
        const int4 d = ((const int4*)i3)[q];
        atomicAdd(&packed_d[a.x * HDIM + b.x], 1u << 24);
        atomicAdd(&packed_d[a.y * HDIM + b.y], 1u << 24);
        atomicAdd(&packed_d[a.z * HDIM + b.z], 1u << 24);
        atomicAdd(&packed_d[a.w * HDIM + b.w], 1u << 24);
        atomicAdd(&packed_r[c.x * HDIM + d.x], 1u << 24);
        atomicAdd(&packed_r[c.y * HDIM + d.y], 1u << 24);
        atomicAdd(&packed_r[c.z * HDIM + d.z], 1u << 24);
        atomicAdd(&packed_r[c.w * HDIM + d.w], 1u << 24);
    }
}

// Stream packed arrays; hist[ch][bin] += count. Register fast-path for the hot
// all-channels-bin0 case (mask=0 pixels) to avoid LDS same-address serialization.
__global__ __launch_bounds__(256) void combine_kernel(
    const unsigned* __restrict__ packed_d, const unsigned* __restrict__ packed_r,
    unsigned* __restrict__ hist)
{
    __shared__ unsigned lhist[6 * BINS];
    for (int t = threadIdx.x; t < 6 * BINS; t += 256) lhist[t] = 0;
    __syncthreads();

    unsigned b0d = 0, b0r = 0;
    const int stride = gridDim.x * 256;
    for (int g = blockIdx.x * 256 + threadIdx.x; g < HH / 4; g += stride) {
        const uint4 wd4 = ((const uint4*)packed_d)[g];
        const uint4 wr4 = ((const uint4*)packed_r)[g];
        const unsigned wd[4] = {wd4.x, wd4.y, wd4.z, wd4.w};
        const unsigned wr[4] = {wr4.x, wr4.y, wr4.z, wr4.w};
#pragma unroll
        for (int k = 0; k < 4; k++) {
            const unsigned cd = wd[k] >> 24;
            if (cd) {
                const unsigned bins = wd[k] & 0xFFFFFFu;
                if (bins == 0) b0d += cd;
                else {
                    atomicAdd(&lhist[           (bins        & 255u)], cd);
                    atomicAdd(&lhist[1 * BINS + ((bins >> 8)  & 255u)], cd);
                    atomicAdd(&lhist[2 * BINS + ((bins >> 16) & 255u)], cd);
                }
            }
            const unsigned cr = wr[k] >> 24;
            if (cr) {
                const unsigned bins = wr[k] & 0xFFFFFFu;
                if (bins == 0) b0r += cr;
                else {
                    atomicAdd(&lhist[3 * BINS + (bins        & 255u)], cr);
                    atomicAdd(&lhist[4 * BINS + ((bins >> 8)  & 255u)], cr);
                    atomicAdd(&lhist[5 * BINS + ((bins >> 16) & 255u)], cr);
                }
            }
        }
    }
    if (b0d) {
        atomicAdd(&lhist[0 * BINS], b0d);
        atomicAdd(&lhist[1 * BINS], b0d);
        atomicAdd(&lhist[2 * BINS], b0d);
    }
    if (b0r) {
        atomicAdd(&lhist[3 * BINS], b0r);
        atomicAdd(&lhist[4 * BINS], b0r);
        atomicAdd(&lhist[5 * BINS], b0r);
    }
    __syncthreads();
    unsigned* h = hist + (blockIdx.x & (NCOPY - 1)) * (6 * BINS);
    for (int t = threadIdx.x; t < 6 * BINS; t += 256) {
        const unsigned v = lhist[t];
        if (v) atomicAdd(&h[t], v);
    }
}

// Fully-parallel CDF + transfer table:
//   integer wave scan (exact) -> parallel float divide -> binary-search interval.
__global__ __launch_bounds__(256) void table_kernel(
    const unsigned* __restrict__ hist, float* __restrict__ tables)
{
    __shared__ float cdf_d[3][BINS];
    __shared__ float cdf_r[3][BINS];
    __shared__ unsigned wsum[4];
    const int t = threadIdx.x;
    const int lane = t & 63;
    const int wid = t >> 6;

    for (int ch = 0; ch < 6; ch++) {
        unsigned x = 0;
#pragma unroll
        for (int cp = 0; cp < NCOPY; cp++) x += hist[cp * (6 * BINS) + ch * BINS + t];
        // wave-inclusive scan (64 lanes)
#pragma unroll
        for (int d = 1; d < 64; d <<= 1) {
            const unsigned y = __shfl_up(x, d, 64);
            if (lane >= d) x += y;
        }
        if (lane == 63) wsum[wid] = x;
        __syncthreads();
        unsigned prefix = 0;
        for (int w = 0; w < wid; w++) prefix += wsum[w];
        x += prefix;
        const float f = (float)x / 2000000.0f;   // exact int < 2^24, single rounding
        if (ch < 3) cdf_d[ch][t] = f;
        else        cdf_r[ch - 3][t] = f;
        __syncthreads();
    }

    for (int c = 0; c < 3; c++) {
        float out;
        if (t == 0)             out = 0.0f;
        else if (t == BINS - 1) out = 255.0f;
        else {
            const float v = cdf_d[c][t];
            const float* arr = cdf_r[c];
            // lower_bound: first k with arr[k] >= v  (arr[255] = 1.0 >= v always)
            int lo = 0, hi = 256;
            while (lo < hi) { const int mid = (lo + hi) >> 1; if (arr[mid] < v) lo = mid + 1; else hi = mid; }
            const int J0 = ((lo > 1) ? lo : 1) - 1;
            // upper_bound: first k with arr[k] > v
            int lo2 = 0, hi2 = 256;
            while (lo2 < hi2) { const int mid = (lo2 + hi2) >> 1; if (arr[mid] <= v) lo2 = mid + 1; else hi2 = mid; }
            const int J1 = ((lo2 - 1) < 254 ? (lo2 - 1) : 254);
            const bool found = (lo2 >= 1) && (J0 <= J1);
            out = found ? (float)(J0 + 1) : (float)t;
        }
        tables[c * BINS + t] = out;
    }
}

// One thread handles 4 pixels across all 3 channels; per-block partial sum
// (no contended double CAS atomic — that was the hidden ~150 us).
__global__ __launch_bounds__(256) void loss_kernel(
    const float* __restrict__ inp, const float* __restrict__ ref,
    const float* __restrict__ msrc, const float* __restrict__ tables_g,
    const unsigned* __restrict__ packed_d, double* __restrict__ partials)
{
    __shared__ float tab[3 * BINS];
    for (int t = threadIdx.x; t < 3 * BINS; t += 256) tab[t] = tables_g[t];
    __syncthreads();

    double local = 0.0;
    const int stride = gridDim.x * 256;
    for (int g = blockIdx.x * 256 + threadIdx.x; g < HH / 4; g += stride) {
        const int p = g * 4;
        const float4 mv = *(const float4*)(msrc + p);
        const uint4 pk4 = *(const uint4*)(packed_d + p);
        const float m[4] = {mv.x, mv.y, mv.z, mv.w};
        const unsigned pw[4] = {pk4.x, pk4.y, pk4.z, pk4.w};
#pragma unroll
        for (int c = 0; c < 3; c++) {
            const float4 rv = *(const float4*)(ref + c * HH + p);
            const float4 iv = *(const float4*)(inp + c * HH + p);
            const float r[4] = {rv.x, rv.y, rv.z, rv.w};
            const float x[4] = {iv.x, iv.y, iv.z, iv.w};
            float s = 0.0f;
#pragma unroll
            for (int k = 0; k < 4; k++) {
                const float mm = m[k];
                const float refm = ((r[k] + 1.0f) * 0.5f) * 255.0f * mm;   // ref_masked
                const float inpm = ((x[k] + 1.0f) * 0.5f) * 255.0f * mm;   // input_masked
                float matchv;
                if (pw[k] >> 24) {                       // pixel was sampled
                    matchv = tab[c * BINS + ((pw[k] >> (8 * c)) & 255u)];  // bin from pack (bit-identical)
                } else {
                    matchv = refm;
                }
                const float d = inpm - matchv * mm;
                s += d * d;
            }
            local += (double)s;
        }
    }

    __shared__ double red[256];
    red[threadIdx.x] = local;
    __syncthreads();
    for (int s2 = 128; s2 > 0; s2 >>= 1) {
        if (threadIdx.x < s2) red[threadIdx.x] += red[threadIdx.x + s2];
        __syncthreads();
    }
    if (threadIdx.x == 0) partials[blockIdx.x] = red[0];
}

__global__ __launch_bounds__(256) void finalize_kernel(
    const double* __restrict__ partials, float* __restrict__ out)
{
    const int t = threadIdx.x;
    double s = partials[t] + partials[t + 256] + partials[t + 512] + partials[t + 768];
    __shared__ double red[256];
    red[t] = s;
    __syncthreads();
    for (int s2 = 128; s2 > 0; s2 >>= 1) {
        if (t < s2) red[t] += red[t + s2];
        __syncthreads();
    }
    if (t == 0) out[0] = (float)(red[0] / (double)(3 * HH));
}

extern "C" void kernel_launch(void* const* d_in, const int* in_sizes, int n_in,
                              void* d_out, int out_size, void* d_ws, size_t ws_size,
                              hipStream_t stream)
{
    const float* input_data  = (const float*)d_in[0];
    const float* target_data = (const float*)d_in[1];
    const float* mask_src    = (const float*)d_in[2];
    const float* mask_tar    = (const float*)d_in[3];
    const int*   i0          = (const int*)d_in[4];
    const int*   i1          = (const int*)d_in[5];
    const int*   i2          = (const int*)d_in[6];
    const int*   i3          = (const int*)d_in[7];
    const float* ref_data    = (const float*)d_in[8];
    float* out = (float*)d_out;

    char* ws = (char*)d_ws;
    double*   partials = (double*)(ws + PART_OFF);
    unsigned* hist     = (unsigned*)(ws + HIST_OFF);
    float*    tables   = (float*)(ws + TAB_OFF);
    unsigned* packed_d = (unsigned*)(ws + PACKED_D_OFF);
    unsigned* packed_r = (unsigned*)(ws + PACKED_R_OFF);

    hipMemsetAsync(ws, 0, WS_ZERO_BYTES, stream);
    pack_kernel<<<2048, 256, 0, stream>>>(ref_data, target_data, mask_src, mask_tar,
                                          packed_d, packed_r);
    scatter_kernel<<<2048, 256, 0, stream>>>(i0, i1, i2, i3, packed_d, packed_r);
    combine_kernel<<<2048, 256, 0, stream>>>(packed_d, packed_r, hist);
    table_kernel<<<1, 256, 0, stream>>>(hist, tables);
    loss_kernel<<<LOSS_BLOCKS, 256, 0, stream>>>(input_data, ref_data, mask_src, tables,
                                                 packed_d, partials);
    finalize_kernel<<<1, 256, 0, stream>>>(partials, out);
}